// Round 7
// baseline (692.791 us; speedup 1.0000x reference)
//
#include <hip/hip_runtime.h>
#include <hip/hip_fp16.h>

// Problem constants (fixed by setup_inputs)
#define HW_N 4096   // 64*64 spatial positions
#define C_IN 512    // channels
#define C_Q  64     // query/key channels
#define NB   4      // batch
#define M_Y  640    // Cq + Cq + C stacked output rows
#define LOG2E 1.4426950408889634f

typedef __attribute__((ext_vector_type(8))) short short8;
typedef __attribute__((ext_vector_type(4))) short short4v;
typedef __attribute__((ext_vector_type(4))) float float4v;
typedef unsigned short ushort_t;

__device__ __forceinline__ ushort_t f2h(float x) {
    return __half_as_ushort(__float2half(x));  // RNE
}
__device__ __forceinline__ float h2f(ushort_t h) {
    return __half2float(__ushort_as_half(h));
}
__device__ __forceinline__ void gl2lds16(const ushort_t* g, ushort_t* l) {
    __builtin_amdgcn_global_load_lds(
        (const __attribute__((address_space(1))) unsigned int*)g,
        (__attribute__((address_space(3))) unsigned int*)l, 16, 0, 0);
}

// ---------------------------------------------------------------------------
// split stacked W = [Wq;Wk;Wv] (640x512 fp32) -> fp16 hi/lo  (once per call;
// Wh/Wl now live in the PERSISTENT region — not overlaid by scores)
// ---------------------------------------------------------------------------
__global__ __launch_bounds__(256) void split_w(const float* __restrict__ Wq,
                                               const float* __restrict__ Wk,
                                               const float* __restrict__ Wv,
                                               ushort_t* __restrict__ Wh,
                                               ushort_t* __restrict__ Wl) {
    int idx = (blockIdx.x * 256 + threadIdx.x) * 4;
#pragma unroll
    for (int e = 0; e < 4; e++) {
        int i = idx + e;
        int m = i >> 9, k = i & 511;
        float v = (m < C_Q) ? Wq[m * C_IN + k]
                 : (m < 2 * C_Q) ? Wk[(m - C_Q) * C_IN + k]
                 : Wv[(size_t)(m - 2 * C_Q) * C_IN + k];
        ushort_t h = f2h(v);
        Wh[i] = h;
        Wl[i] = f2h(v - h2f(h));
    }
}

// ---------------------------------------------------------------------------
// transpose + split: x [512][4096] fp32 -> xT hi/lo [4096][512] fp16
// Also zeroes D[4096] (rowsum accumulator) in the first 16 blocks of row y==0.
// ---------------------------------------------------------------------------
__global__ __launch_bounds__(256) void split_x(const float* __restrict__ x,
                                               ushort_t* __restrict__ xTh,
                                               ushort_t* __restrict__ xTl,
                                               float* __restrict__ D) {
    if (blockIdx.y == 0 && blockIdx.x < 16) D[blockIdx.x * 256 + threadIdx.x] = 0.f;

    __shared__ float tile[64][65];
    const int n0 = blockIdx.x * 64, k0 = blockIdx.y * 64;
    const int t = threadIdx.x;
#pragma unroll
    for (int it = 0; it < 4; it++) {
        int e = t + it * 256;
        int r = e >> 4, c4 = (e & 15) << 2;
        float4 v = *(const float4*)(x + (size_t)(k0 + r) * HW_N + n0 + c4);
        tile[r][c4 + 0] = v.x; tile[r][c4 + 1] = v.y;
        tile[r][c4 + 2] = v.z; tile[r][c4 + 3] = v.w;
    }
    __syncthreads();
    const int rr = t >> 2, kq = (t & 3) << 4;
    ushort_t h[16], l[16];
#pragma unroll
    for (int j = 0; j < 16; j++) {
        float v = tile[kq + j][rr];
        h[j] = f2h(v);
        l[j] = f2h(v - h2f(h[j]));
    }
    size_t o = (size_t)(n0 + rr) * C_IN + k0 + kq;
    *(uint4*)(xTh + o) = *(uint4*)h;
    *(uint4*)(xTh + o + 8) = *(uint4*)(h + 8);
    *(uint4*)(xTl + o) = *(uint4*)l;
    *(uint4*)(xTl + o + 8) = *(uint4*)(l + 8);
}

// ---------------------------------------------------------------------------
// 3-term fp16 hi/lo GEMM: C[m,n] = sum_k A[m,k]*B[n,k]
// 128x128 block tile, 4 waves, 16x16x32 f16 MFMA.
// EPI 0: Y epilogue (+bias, fp16 h/l; m<128 -> qkT transposed, else V)
// EPI 1: fp32 store (scores) + fused exp-rowsum atomicAdd into Dsum
// ---------------------------------------------------------------------------
template <int EPI>
__global__ __launch_bounds__(256) void mfma3(
    const ushort_t* __restrict__ Ah, const ushort_t* __restrict__ Al, int aStride,
    const ushort_t* __restrict__ Bh, const ushort_t* __restrict__ Bl, int bStride,
    int kLen,
    const float* __restrict__ bq, const float* __restrict__ bk,
    const float* __restrict__ bv,
    ushort_t* __restrict__ qkTh, ushort_t* __restrict__ qkTl,
    ushort_t* __restrict__ Vh, ushort_t* __restrict__ Vl,
    float* __restrict__ outF, float* __restrict__ Dsum) {
    __shared__ ushort_t sAh[128 * 32];
    __shared__ ushort_t sAl[128 * 32];
    __shared__ ushort_t sBh[128 * 32];
    __shared__ ushort_t sBl[128 * 32];

    const int tid = threadIdx.x, w = tid >> 6, lane = tid & 63;
    const int quad = lane >> 4, lr = lane & 15;
    const int m0 = blockIdx.y * 128, n0 = blockIdx.x * 128;

    const ushort_t* src;
    ushort_t* dst;
    int stride, rowBase;
    if (w == 0)      { src = Ah; dst = sAh; stride = aStride; rowBase = m0; }
    else if (w == 1) { src = Al; dst = sAl; stride = aStride; rowBase = m0; }
    else if (w == 2) { src = Bh; dst = sBh; stride = bStride; rowBase = n0; }
    else             { src = Bl; dst = sBl; stride = bStride; rowBase = n0; }
    const int cr = lane >> 2, kp = (lane & 3) << 3;
    const ushort_t* gk = src + (size_t)(rowBase + cr) * stride + kp;

    const int wm = (w & 1) * 64, wn = (w >> 1) * 64;

    float4v acc[4][4];
#pragma unroll
    for (int i = 0; i < 4; i++)
#pragma unroll
        for (int j = 0; j < 4; j++) acc[i][j] = (float4v){0.f, 0.f, 0.f, 0.f};

    for (int kk = 0; kk < kLen; kk += 32) {
#pragma unroll
        for (int c = 0; c < 8; c++)
            gl2lds16(gk + (size_t)(c * 16) * stride + kk, dst + c * 512);
        __syncthreads();

        short8 ah[4], al[4], bh[4], bl[4];
#pragma unroll
        for (int i = 0; i < 4; i++) {
            ah[i] = *(const short8*)&sAh[(wm + i * 16 + lr) * 32 + quad * 8];
            al[i] = *(const short8*)&sAl[(wm + i * 16 + lr) * 32 + quad * 8];
            bh[i] = *(const short8*)&sBh[(wn + i * 16 + lr) * 32 + quad * 8];
            bl[i] = *(const short8*)&sBl[(wn + i * 16 + lr) * 32 + quad * 8];
        }
#pragma unroll
        for (int i = 0; i < 4; i++)
#pragma unroll
            for (int j = 0; j < 4; j++) {
                acc[i][j] = __builtin_amdgcn_mfma_f32_16x16x32_f16(ah[i], bh[j], acc[i][j], 0, 0, 0);
                acc[i][j] = __builtin_amdgcn_mfma_f32_16x16x32_f16(ah[i], bl[j], acc[i][j], 0, 0, 0);
                acc[i][j] = __builtin_amdgcn_mfma_f32_16x16x32_f16(al[i], bh[j], acc[i][j], 0, 0, 0);
            }
        __syncthreads();
    }

    if (EPI == 0) {
#pragma unroll
        for (int i = 0; i < 4; i++)
#pragma unroll
            for (int j = 0; j < 4; j++)
#pragma unroll
                for (int r = 0; r < 4; r++) {
                    const int m = m0 + wm + i * 16 + quad * 4 + r;
                    const int n = n0 + wn + j * 16 + lr;
                    float bi = (m < C_Q) ? bq[m]
                              : (m < 2 * C_Q) ? bk[m - C_Q] : bv[m - 2 * C_Q];
                    float v = acc[i][j][r] + bi;
                    ushort_t h = f2h(v);
                    ushort_t lo = f2h(v - h2f(h));
                    if (m < 2 * C_Q) {
                        qkTh[(size_t)n * (2 * C_Q) + m] = h;
                        qkTl[(size_t)n * (2 * C_Q) + m] = lo;
                    } else {
                        Vh[(size_t)(m - 2 * C_Q) * HW_N + n] = h;
                        Vl[(size_t)(m - 2 * C_Q) * HW_N + n] = lo;
                    }
                }
    } else {
        // store S + fused per-row exp-sum partials
#pragma unroll
        for (int i = 0; i < 4; i++) {
#pragma unroll
            for (int r = 0; r < 4; r++) {
                float s = 0.f;
#pragma unroll
                for (int j = 0; j < 4; j++) {
                    const int m = m0 + wm + i * 16 + quad * 4 + r;
                    const int n = n0 + wn + j * 16 + lr;
                    outF[(size_t)m * HW_N + n] = acc[i][j][r];
                    s += __expf(acc[i][j][r]);
                }
                s += __shfl_xor(s, 1);
                s += __shfl_xor(s, 2);
                s += __shfl_xor(s, 4);
                s += __shfl_xor(s, 8);
                if (lr == 0)
                    atomicAdd(&Dsum[m0 + wm + i * 16 + quad * 4 + r], s);
            }
        }
    }
}

// ---------------------------------------------------------------------------
// feat GEMM: out[m,n] += alpha * sum_k (Vh+Vl)[m,k] * P[n,k],
//   P[n,k] = f16( exp2(S[n,k]*log2e - log2 D[n]) )
// 128x128 tile, 4 waves. Waves 0/1 stage V h/l async; ALL threads convert the
// 128x32 S tile once into fp16 LDS (global->reg->LDS, 16 elems/thread).
// Swizzles: V 16B-unit quad^((row>>1)&3) (2-way, free); P 8B-unit u^(row&7).
// kparts=4 via blockIdx.z; partials atomicAdd'ed into pre-zeroed out.
// ---------------------------------------------------------------------------
__global__ __launch_bounds__(256) void feat4(const ushort_t* __restrict__ Vh,
                                             const ushort_t* __restrict__ Vl,
                                             const float* __restrict__ S,
                                             const float* __restrict__ D,
                                             const float* __restrict__ alpha,
                                             float* __restrict__ out, int kLen) {
    __shared__ ushort_t sVh[128 * 32];
    __shared__ ushort_t sVl[128 * 32];
    __shared__ ushort_t sP [128 * 32];

    const int tid = threadIdx.x, w = tid >> 6, lane = tid & 63;
    const int quad = lane >> 4, lr = lane & 15;
    const int m0 = blockIdx.y * 128, n0 = blockIdx.x * 128;
    const int k0 = blockIdx.z * kLen;

    // V staging (waves 0/1), swizzled 16B units
    const int crv = lane >> 2, uv = lane & 3;
    const ushort_t* gV = ((w & 1) ? Vl : Vh) +
        (size_t)(m0 + crv) * HW_N + ((uv ^ ((crv >> 1) & 3)) << 3) + k0;
    ushort_t* sV = (w & 1) ? sVl : sVh;
    const bool stageV = (w < 2);

    // P conversion geometry: thread handles rows pr+32c (c=0..3), 4-float unit pu
    const int pr = tid >> 3, pu = tid & 7;
    const float* gS = S + (size_t)(n0 + pr) * HW_N + k0 + pu * 4;
    const int pphys = (pu ^ (pr & 7)) << 2;  // constant across c (32c % 8 == 0)
    float lrw[4];
#pragma unroll
    for (int c = 0; c < 4; c++) lrw[c] = -log2f(D[n0 + pr + 32 * c]);

    const int wm = (w & 1) * 64, wn = (w >> 1) * 64;

    float4v acc[4][4];
#pragma unroll
    for (int i = 0; i < 4; i++)
#pragma unroll
        for (int j = 0; j < 4; j++) acc[i][j] = (float4v){0.f, 0.f, 0.f, 0.f};

    for (int kk = 0; kk < kLen; kk += 32) {
        if (stageV) {
#pragma unroll
            for (int c = 0; c < 8; c++)
                gl2lds16(gV + (size_t)(c * 16) * HW_N + kk, sV + c * 512);
        }
        // convert S -> P fp16 into LDS (each element exactly once per block)
#pragma unroll
        for (int c = 0; c < 4; c++) {
            float4 s4 = *(const float4*)(gS + (size_t)(32 * c) * HW_N + kk);
            ushort_t h4[4];
            h4[0] = f2h(exp2f(fmaf(s4.x, LOG2E, lrw[c])));
            h4[1] = f2h(exp2f(fmaf(s4.y, LOG2E, lrw[c])));
            h4[2] = f2h(exp2f(fmaf(s4.z, LOG2E, lrw[c])));
            h4[3] = f2h(exp2f(fmaf(s4.w, LOG2E, lrw[c])));
            *(short4v*)&sP[(pr + 32 * c) * 32 + pphys] = *(short4v*)h4;
        }
        __syncthreads();

        short8 ah[4], al[4], bh[4];
#pragma unroll
        for (int i = 0; i < 4; i++) {
            const int row = wm + i * 16 + lr;
            const int up = (quad ^ ((lr >> 1) & 3)) << 3;
            ah[i] = *(const short8*)&sVh[row * 32 + up];
            al[i] = *(const short8*)&sVl[row * 32 + up];
        }
#pragma unroll
        for (int j = 0; j < 4; j++) {
            const int row = wn + j * 16 + lr;
            const int p0 = (((2 * quad)     ^ (lr & 7)) << 2);
            const int p1 = (((2 * quad + 1) ^ (lr & 7)) << 2);
            short4v x0 = *(const short4v*)&sP[row * 32 + p0];
            short4v x1 = *(const short4v*)&sP[row * 32 + p1];
            bh[j] = (short8){x0[0], x0[1], x0[2], x0[3], x1[0], x1[1], x1[2], x1[3]};
        }
#pragma unroll
        for (int i = 0; i < 4; i++)
#pragma unroll
            for (int j = 0; j < 4; j++) {
                acc[i][j] = __builtin_amdgcn_mfma_f32_16x16x32_f16(ah[i], bh[j], acc[i][j], 0, 0, 0);
                acc[i][j] = __builtin_amdgcn_mfma_f32_16x16x32_f16(al[i], bh[j], acc[i][j], 0, 0, 0);
            }
        __syncthreads();
    }

    const float a = alpha[0];
#pragma unroll
    for (int i = 0; i < 4; i++)
#pragma unroll
        for (int j = 0; j < 4; j++)
#pragma unroll
            for (int r = 0; r < 4; r++) {
                const int m = m0 + wm + i * 16 + quad * 4 + r;
                const int n = n0 + wn + j * 16 + lr;
                atomicAdd(&out[(size_t)m * HW_N + n], a * acc[i][j][r]);
            }
}

// ---------------------------------------------------------------------------

extern "C" void kernel_launch(void* const* d_in, const int* in_sizes, int n_in,
                              void* d_out, int out_size, void* d_ws, size_t ws_size,
                              hipStream_t stream) {
    const float* x     = (const float*)d_in[0];
    const float* Wq    = (const float*)d_in[1];
    const float* bq    = (const float*)d_in[2];
    const float* Wk    = (const float*)d_in[3];
    const float* bk    = (const float*)d_in[4];
    const float* Wv    = (const float*)d_in[5];
    const float* bv    = (const float*)d_in[6];
    const float* alpha = (const float*)d_in[7];
    float* out = (float*)d_out;

    // ws layout (persistent region first — nothing here is overlaid):
    //   D         : 4096 fp32 rowsum               (16 KB)
    //   qkTh/qkTl : 4096 x 128 fp16 each           (2.1 MB)
    //   Vh/Vl     : 512 x 4096 fp16 each           (8.4 MB)
    //   Wh/Wl     : 640 x 512 fp16 each            (1.3 MB)   <- moved out of overlay
    //   scores    : 4096 x 4096 fp32               (67.1 MB)
    //     overlay (dead before scores written): xTh/xTl (8.4 MB)
    float* D = (float*)d_ws;
    ushort_t* qkTh = (ushort_t*)(D + HW_N);
    ushort_t* qkTl = qkTh + (size_t)HW_N * 2 * C_Q;
    ushort_t* Vh   = qkTl + (size_t)HW_N * 2 * C_Q;
    ushort_t* Vl   = Vh + (size_t)C_IN * HW_N;
    ushort_t* Wh   = Vl + (size_t)C_IN * HW_N;
    ushort_t* Wl   = Wh + (size_t)M_Y * C_IN;
    float* scores  = (float*)(Wl + (size_t)M_Y * C_IN);

    ushort_t* xTh = (ushort_t*)scores;
    ushort_t* xTl = xTh + (size_t)HW_N * C_IN;

    // zero output (feat4 accumulates atomically) — every call, graph-safe
    hipMemsetAsync(out, 0, (size_t)out_size * sizeof(float), stream);

    split_w<<<dim3(M_Y * C_IN / 4 / 256), dim3(256), 0, stream>>>(Wq, Wk, Wv, Wh, Wl);

    for (int b = 0; b < NB; b++) {
        const float* xb = x + (size_t)b * C_IN * HW_N;
        float* outb = out + (size_t)b * C_IN * HW_N;

        split_x<<<dim3(HW_N / 64, C_IN / 64), dim3(256), 0, stream>>>(xb, xTh, xTl, D);

        // Y = W*x + b -> qkT (transposed, m<128) and V (m>=128), fp16 h/l
        mfma3<0><<<dim3(HW_N / 128, M_Y / 128), dim3(256), 0, stream>>>(
            Wh, Wl, C_IN, xTh, xTl, C_IN, C_IN,
            bq, bk, bv, qkTh, qkTl, Vh, Vl, nullptr, nullptr);

        // S[i,j] = sum_c q[c,i]k[c,j]  (fp32) + fused exp-rowsum into D
        mfma3<1><<<dim3(HW_N / 128, HW_N / 128), dim3(256), 0, stream>>>(
            qkTh, qkTl, 2 * C_Q, qkTh + C_Q, qkTl + C_Q, 2 * C_Q, C_Q,
            nullptr, nullptr, nullptr, nullptr, nullptr, nullptr, nullptr,
            scores, D);

        // out[c,i] += alpha * sum_j (Vh+Vl)[c,j] * f16(exp(S[i,j])/D[i])
        feat4<<<dim3(HW_N / 128, C_IN / 128, 4), dim3(256), 0, stream>>>(
            Vh, Vl, scores, D, alpha, outb, HW_N / 4);
    }
}

// Round 8
// 614.102 us; speedup vs baseline: 1.1281x; 1.1281x over previous
//
#include <hip/hip_runtime.h>
#include <hip/hip_fp16.h>

// Problem constants (fixed by setup_inputs)
#define HW_N 4096   // 64*64 spatial positions
#define C_IN 512    // channels
#define C_Q  64     // query/key channels
#define NB   4      // batch
#define M_Y  640    // Cq + Cq + C stacked output rows
#define LOG2E 1.4426950408889634f

typedef __attribute__((ext_vector_type(8))) short short8;
typedef __attribute__((ext_vector_type(4))) short short4v;
typedef __attribute__((ext_vector_type(4))) float float4v;
typedef unsigned short ushort_t;

__device__ __forceinline__ ushort_t f2h(float x) {
    return __half_as_ushort(__float2half(x));  // RNE
}
__device__ __forceinline__ float h2f(ushort_t h) {
    return __half2float(__ushort_as_half(h));
}
__device__ __forceinline__ void gl2lds16(const ushort_t* g, ushort_t* l) {
    __builtin_amdgcn_global_load_lds(
        (const __attribute__((address_space(1))) unsigned int*)g,
        (__attribute__((address_space(3))) unsigned int*)l, 16, 0, 0);
}

// ---------------------------------------------------------------------------
// split stacked W = [Wq;Wk;Wv] (640x512 fp32) -> fp16 hi/lo (persistent region)
// ---------------------------------------------------------------------------
__global__ __launch_bounds__(256) void split_w(const float* __restrict__ Wq,
                                               const float* __restrict__ Wk,
                                               const float* __restrict__ Wv,
                                               ushort_t* __restrict__ Wh,
                                               ushort_t* __restrict__ Wl) {
    int idx = (blockIdx.x * 256 + threadIdx.x) * 4;
#pragma unroll
    for (int e = 0; e < 4; e++) {
        int i = idx + e;
        int m = i >> 9, k = i & 511;
        float v = (m < C_Q) ? Wq[m * C_IN + k]
                 : (m < 2 * C_Q) ? Wk[(m - C_Q) * C_IN + k]
                 : Wv[(size_t)(m - 2 * C_Q) * C_IN + k];
        ushort_t h = f2h(v);
        Wh[i] = h;
        Wl[i] = f2h(v - h2f(h));
    }
}

// ---------------------------------------------------------------------------
// transpose + split: x [512][4096] fp32 -> xT hi/lo [4096][512] fp16
// Also zeroes D[4096] (rowsum accumulator) in the first 16 blocks of row y==0.
// ---------------------------------------------------------------------------
__global__ __launch_bounds__(256) void split_x(const float* __restrict__ x,
                                               ushort_t* __restrict__ xTh,
                                               ushort_t* __restrict__ xTl,
                                               float* __restrict__ D) {
    if (blockIdx.y == 0 && blockIdx.x < 16) D[blockIdx.x * 256 + threadIdx.x] = 0.f;

    __shared__ float tile[64][65];
    const int n0 = blockIdx.x * 64, k0 = blockIdx.y * 64;
    const int t = threadIdx.x;
#pragma unroll
    for (int it = 0; it < 4; it++) {
        int e = t + it * 256;
        int r = e >> 4, c4 = (e & 15) << 2;
        float4 v = *(const float4*)(x + (size_t)(k0 + r) * HW_N + n0 + c4);
        tile[r][c4 + 0] = v.x; tile[r][c4 + 1] = v.y;
        tile[r][c4 + 2] = v.z; tile[r][c4 + 3] = v.w;
    }
    __syncthreads();
    const int rr = t >> 2, kq = (t & 3) << 4;
    ushort_t h[16], l[16];
#pragma unroll
    for (int j = 0; j < 16; j++) {
        float v = tile[kq + j][rr];
        h[j] = f2h(v);
        l[j] = f2h(v - h2f(h[j]));
    }
    size_t o = (size_t)(n0 + rr) * C_IN + k0 + kq;
    *(uint4*)(xTh + o) = *(uint4*)h;
    *(uint4*)(xTh + o + 8) = *(uint4*)(h + 8);
    *(uint4*)(xTl + o) = *(uint4*)l;
    *(uint4*)(xTl + o + 8) = *(uint4*)(l + 8);
}

// ---------------------------------------------------------------------------
// 3-term fp16 hi/lo GEMM: C[m,n] = sum_k A[m,k]*B[n,k]
// 128x128 block tile, 4 waves, 16x16x32 f16 MFMA.
// EPI 0: Y epilogue (+bias, fp16 h/l; m<128 -> qkT transposed, else V)
// EPI 1: fp32 store (scores) + fused exp-rowsum atomicAdd into Dsum
// ---------------------------------------------------------------------------
template <int EPI>
__global__ __launch_bounds__(256) void mfma3(
    const ushort_t* __restrict__ Ah, const ushort_t* __restrict__ Al, int aStride,
    const ushort_t* __restrict__ Bh, const ushort_t* __restrict__ Bl, int bStride,
    int kLen,
    const float* __restrict__ bq, const float* __restrict__ bk,
    const float* __restrict__ bv,
    ushort_t* __restrict__ qkTh, ushort_t* __restrict__ qkTl,
    ushort_t* __restrict__ Vh, ushort_t* __restrict__ Vl,
    float* __restrict__ outF, float* __restrict__ Dsum) {
    __shared__ ushort_t sAh[128 * 32];
    __shared__ ushort_t sAl[128 * 32];
    __shared__ ushort_t sBh[128 * 32];
    __shared__ ushort_t sBl[128 * 32];

    const int tid = threadIdx.x, w = tid >> 6, lane = tid & 63;
    const int quad = lane >> 4, lr = lane & 15;
    const int m0 = blockIdx.y * 128, n0 = blockIdx.x * 128;

    const ushort_t* src;
    ushort_t* dst;
    int stride, rowBase;
    if (w == 0)      { src = Ah; dst = sAh; stride = aStride; rowBase = m0; }
    else if (w == 1) { src = Al; dst = sAl; stride = aStride; rowBase = m0; }
    else if (w == 2) { src = Bh; dst = sBh; stride = bStride; rowBase = n0; }
    else             { src = Bl; dst = sBl; stride = bStride; rowBase = n0; }
    const int cr = lane >> 2, kp = (lane & 3) << 3;
    const ushort_t* gk = src + (size_t)(rowBase + cr) * stride + kp;

    const int wm = (w & 1) * 64, wn = (w >> 1) * 64;

    float4v acc[4][4];
#pragma unroll
    for (int i = 0; i < 4; i++)
#pragma unroll
        for (int j = 0; j < 4; j++) acc[i][j] = (float4v){0.f, 0.f, 0.f, 0.f};

    for (int kk = 0; kk < kLen; kk += 32) {
#pragma unroll
        for (int c = 0; c < 8; c++)
            gl2lds16(gk + (size_t)(c * 16) * stride + kk, dst + c * 512);
        __syncthreads();

        short8 ah[4], al[4], bh[4], bl[4];
#pragma unroll
        for (int i = 0; i < 4; i++) {
            ah[i] = *(const short8*)&sAh[(wm + i * 16 + lr) * 32 + quad * 8];
            al[i] = *(const short8*)&sAl[(wm + i * 16 + lr) * 32 + quad * 8];
            bh[i] = *(const short8*)&sBh[(wn + i * 16 + lr) * 32 + quad * 8];
            bl[i] = *(const short8*)&sBl[(wn + i * 16 + lr) * 32 + quad * 8];
        }
#pragma unroll
        for (int i = 0; i < 4; i++)
#pragma unroll
            for (int j = 0; j < 4; j++) {
                acc[i][j] = __builtin_amdgcn_mfma_f32_16x16x32_f16(ah[i], bh[j], acc[i][j], 0, 0, 0);
                acc[i][j] = __builtin_amdgcn_mfma_f32_16x16x32_f16(ah[i], bl[j], acc[i][j], 0, 0, 0);
                acc[i][j] = __builtin_amdgcn_mfma_f32_16x16x32_f16(al[i], bh[j], acc[i][j], 0, 0, 0);
            }
        __syncthreads();
    }

    if (EPI == 0) {
#pragma unroll
        for (int i = 0; i < 4; i++)
#pragma unroll
            for (int j = 0; j < 4; j++)
#pragma unroll
                for (int r = 0; r < 4; r++) {
                    const int m = m0 + wm + i * 16 + quad * 4 + r;
                    const int n = n0 + wn + j * 16 + lr;
                    float bi = (m < C_Q) ? bq[m]
                              : (m < 2 * C_Q) ? bk[m - C_Q] : bv[m - 2 * C_Q];
                    float v = acc[i][j][r] + bi;
                    ushort_t h = f2h(v);
                    ushort_t lo = f2h(v - h2f(h));
                    if (m < 2 * C_Q) {
                        qkTh[(size_t)n * (2 * C_Q) + m] = h;
                        qkTl[(size_t)n * (2 * C_Q) + m] = lo;
                    } else {
                        Vh[(size_t)(m - 2 * C_Q) * HW_N + n] = h;
                        Vl[(size_t)(m - 2 * C_Q) * HW_N + n] = lo;
                    }
                }
    } else {
        // store S + fused per-row exp-sum partials
#pragma unroll
        for (int i = 0; i < 4; i++) {
#pragma unroll
            for (int r = 0; r < 4; r++) {
                float s = 0.f;
#pragma unroll
                for (int j = 0; j < 4; j++) {
                    const int m = m0 + wm + i * 16 + quad * 4 + r;
                    const int n = n0 + wn + j * 16 + lr;
                    outF[(size_t)m * HW_N + n] = acc[i][j][r];
                    s += __expf(acc[i][j][r]);
                }
                s += __shfl_xor(s, 1);
                s += __shfl_xor(s, 2);
                s += __shfl_xor(s, 4);
                s += __shfl_xor(s, 8);
                if (lr == 0)
                    atomicAdd(&Dsum[m0 + wm + i * 16 + quad * 4 + r], s);
            }
        }
    }
}

// ---------------------------------------------------------------------------
// feat GEMM, software-pipelined: res[m,n] = sum_k (Vh+Vl)[m,k] * P[n,k],
//   P[n,k] = f16( exp2(S[n,k]*log2e - log2 D[n]) )
// 128x128 tile, 4 waves, 16x16x32 f16 MFMA.
// Double-buffered V (global_load_lds) + reg-prefetched S, ONE barrier/iter.
// Issues for iter k+1 go out AFTER the barrier of iter k, so the mandatory
// vmcnt(0) drain at barrier k+1 hits loads that flew through a full MFMA
// section. blockIdx.z==0 stores to out, z>0 to part[z-1] (no atomics).
// ---------------------------------------------------------------------------
__global__ __launch_bounds__(256) void feat5(const ushort_t* __restrict__ Vh,
                                             const ushort_t* __restrict__ Vl,
                                             const float* __restrict__ S,
                                             const float* __restrict__ D,
                                             float* __restrict__ out,
                                             float* __restrict__ part,
                                             int kLen) {
    __shared__ ushort_t sVh[2][4096];
    __shared__ ushort_t sVl[2][4096];
    __shared__ ushort_t sP [2][4096];

    const int tid = threadIdx.x, w = tid >> 6, lane = tid & 63;
    const int quad = lane >> 4, lr = lane & 15;
    const int m0 = blockIdx.y * 128, n0 = blockIdx.x * 128;
    const int k0 = blockIdx.z * kLen;

    // V staging: waves 0-1 handle Vh chunks 0..7, waves 2-3 handle Vl chunks 0..7
    const int crv = lane >> 2, uv = lane & 3;
    const int vcol = (uv ^ ((crv >> 1) & 3)) << 3;   // swizzled 16B unit
    const ushort_t* gVsrc[4];
    int sOfs[4];
    const ushort_t* vbase = (w < 2) ? Vh : Vl;
#pragma unroll
    for (int c = 0; c < 4; c++) {
        const int chunk = ((w & 1) * 4 + c);         // 0..7 within h or l
        gVsrc[c] = vbase + (size_t)(m0 + chunk * 16 + crv) * HW_N + vcol + k0;
        sOfs[c] = chunk * 512;
    }

    // S prefetch geometry: thread owns rows pr+32c (c=0..3), 4-float unit pu
    const int pr = tid >> 3, pu = tid & 7;
    const float* gS = S + (size_t)(n0 + pr) * HW_N + k0 + pu * 4;
    const int pphys = (pu ^ (pr & 7)) << 2;
    float lrw[4];
#pragma unroll
    for (int c = 0; c < 4; c++) lrw[c] = -log2f(D[n0 + pr + 32 * c]);

    const int wm = (w & 1) * 64, wn = (w >> 1) * 64;

    float4 sreg[4];
    // prologue: stage V(0) into buf0, load S(0) into regs
    {
        ushort_t* db = ((w < 2) ? sVh : sVl)[0];
#pragma unroll
        for (int c = 0; c < 4; c++) gl2lds16(gVsrc[c], db + sOfs[c]);
#pragma unroll
        for (int c = 0; c < 4; c++)
            sreg[c] = *(const float4*)(gS + (size_t)(32 * c) * HW_N);
    }
    __syncthreads();  // V(0)+S(0) drained

    float4v acc[4][4];
#pragma unroll
    for (int i = 0; i < 4; i++)
#pragma unroll
        for (int j = 0; j < 4; j++) acc[i][j] = (float4v){0.f, 0.f, 0.f, 0.f};

    const int nIter = kLen >> 5;
    for (int it = 0; it < nIter; ++it) {
        const int kk = it << 5;
        const int cur = it & 1, nxt = cur ^ 1;

        // convert S(it) regs -> sP[cur]
#pragma unroll
        for (int c = 0; c < 4; c++) {
            ushort_t h4[4];
            h4[0] = f2h(exp2f(fmaf(sreg[c].x, LOG2E, lrw[c])));
            h4[1] = f2h(exp2f(fmaf(sreg[c].y, LOG2E, lrw[c])));
            h4[2] = f2h(exp2f(fmaf(sreg[c].z, LOG2E, lrw[c])));
            h4[3] = f2h(exp2f(fmaf(sreg[c].w, LOG2E, lrw[c])));
            *(short4v*)&sP[cur][(pr + 32 * c) * 32 + pphys] = *(short4v*)h4;
        }
        __syncthreads();  // sP[cur] visible; V(it) (in flight a full iter) drained

        // issue next iteration's loads — they fly during this MFMA section
        if (it + 1 < nIter) {
            ushort_t* db = ((w < 2) ? sVh : sVl)[nxt];
#pragma unroll
            for (int c = 0; c < 4; c++) gl2lds16(gVsrc[c] + kk + 32, db + sOfs[c]);
#pragma unroll
            for (int c = 0; c < 4; c++)
                sreg[c] = *(const float4*)(gS + (size_t)(32 * c) * HW_N + kk + 32);
        }

        short8 ah[4], al[4], bh[4];
#pragma unroll
        for (int i = 0; i < 4; i++) {
            const int row = wm + i * 16 + lr;
            const int up = (quad ^ ((lr >> 1) & 3)) << 3;
            ah[i] = *(const short8*)&sVh[cur][row * 32 + up];
            al[i] = *(const short8*)&sVl[cur][row * 32 + up];
        }
#pragma unroll
        for (int j = 0; j < 4; j++) {
            const int row = wn + j * 16 + lr;
            const int p0 = (((2 * quad)     ^ (lr & 7)) << 2);
            const int p1 = (((2 * quad + 1) ^ (lr & 7)) << 2);
            short4v x0 = *(const short4v*)&sP[cur][row * 32 + p0];
            short4v x1 = *(const short4v*)&sP[cur][row * 32 + p1];
            bh[j] = (short8){x0[0], x0[1], x0[2], x0[3], x1[0], x1[1], x1[2], x1[3]};
        }
#pragma unroll
        for (int i = 0; i < 4; i++)
#pragma unroll
            for (int j = 0; j < 4; j++) {
                acc[i][j] = __builtin_amdgcn_mfma_f32_16x16x32_f16(ah[i], bh[j], acc[i][j], 0, 0, 0);
                acc[i][j] = __builtin_amdgcn_mfma_f32_16x16x32_f16(al[i], bh[j], acc[i][j], 0, 0, 0);
            }
        // no trailing barrier: buffer parity + next barrier's lgkm drain cover WAR
    }

    float* o = (blockIdx.z == 0) ? out
             : (part + (size_t)(blockIdx.z - 1) * ((size_t)C_IN * HW_N));
#pragma unroll
    for (int i = 0; i < 4; i++)
#pragma unroll
        for (int j = 0; j < 4; j++)
#pragma unroll
            for (int r = 0; r < 4; r++) {
                const int m = m0 + wm + i * 16 + quad * 4 + r;
                const int n = n0 + wn + j * 16 + lr;
                o[(size_t)m * HW_N + n] = acc[i][j][r];
            }
}

// out = alpha * (out + p0 + p1 + p2), float4-vectorized
__global__ __launch_bounds__(256) void reduce_alpha3(float* __restrict__ out,
                                                     const float4* __restrict__ part,
                                                     size_t stride4,
                                                     const float* __restrict__ alpha) {
    const size_t i = (size_t)blockIdx.x * 256 + threadIdx.x;
    const float a = alpha[0];
    float4* out4 = (float4*)out;
    float4 s = out4[i];
    float4 p0 = part[i];
    float4 p1 = part[i + stride4];
    float4 p2 = part[i + 2 * stride4];
    float4 o;
    o.x = a * (s.x + p0.x + p1.x + p2.x);
    o.y = a * (s.y + p0.y + p1.y + p2.y);
    o.z = a * (s.z + p0.z + p1.z + p2.z);
    o.w = a * (s.w + p0.w + p1.w + p2.w);
    out4[i] = o;
}

// ---------------------------------------------------------------------------

extern "C" void kernel_launch(void* const* d_in, const int* in_sizes, int n_in,
                              void* d_out, int out_size, void* d_ws, size_t ws_size,
                              hipStream_t stream) {
    const float* x     = (const float*)d_in[0];
    const float* Wq    = (const float*)d_in[1];
    const float* bq    = (const float*)d_in[2];
    const float* Wk    = (const float*)d_in[3];
    const float* bk    = (const float*)d_in[4];
    const float* Wv    = (const float*)d_in[5];
    const float* bv    = (const float*)d_in[6];
    const float* alpha = (const float*)d_in[7];
    float* out = (float*)d_out;

    // ws layout (persistent region first — nothing here is overlaid):
    //   D         : 4096 fp32 rowsum               (16 KB)
    //   qkTh/qkTl : 4096 x 128 fp16 each           (2.0 MB)
    //   Vh/Vl     : 512 x 4096 fp16 each           (8.0 MB)
    //   Wh/Wl     : 640 x 512 fp16 each            (1.3 MB)
    //   scores    : 4096 x 4096 fp32               (67.1 MB)
    //     overlay (dead before scores written): xTh/xTl (8.4 MB)
    //   part      : 3 x 512 x 4096 fp32            (25.2 MB)  [z=1..3 partials]
    float* D = (float*)d_ws;
    ushort_t* qkTh = (ushort_t*)(D + HW_N);
    ushort_t* qkTl = qkTh + (size_t)HW_N * 2 * C_Q;
    ushort_t* Vh   = qkTl + (size_t)HW_N * 2 * C_Q;
    ushort_t* Vl   = Vh + (size_t)C_IN * HW_N;
    ushort_t* Wh   = Vl + (size_t)C_IN * HW_N;
    ushort_t* Wl   = Wh + (size_t)M_Y * C_IN;
    float* scores  = (float*)(Wl + (size_t)M_Y * C_IN);
    float* part    = scores + (size_t)HW_N * HW_N;

    ushort_t* xTh = (ushort_t*)scores;
    ushort_t* xTl = xTh + (size_t)HW_N * C_IN;

    split_w<<<dim3(M_Y * C_IN / 4 / 256), dim3(256), 0, stream>>>(Wq, Wk, Wv, Wh, Wl);

    for (int b = 0; b < NB; b++) {
        const float* xb = x + (size_t)b * C_IN * HW_N;
        float* outb = out + (size_t)b * C_IN * HW_N;

        split_x<<<dim3(HW_N / 64, C_IN / 64), dim3(256), 0, stream>>>(xb, xTh, xTl, D);

        // Y = W*x + b -> qkT (transposed, m<128) and V (m>=128), fp16 h/l
        mfma3<0><<<dim3(HW_N / 128, M_Y / 128), dim3(256), 0, stream>>>(
            Wh, Wl, C_IN, xTh, xTl, C_IN, C_IN,
            bq, bk, bv, qkTh, qkTl, Vh, Vl, nullptr, nullptr);

        // S[i,j] = sum_c q[c,i]k[c,j]  (fp32) + fused exp-rowsum into D
        mfma3<1><<<dim3(HW_N / 128, HW_N / 128), dim3(256), 0, stream>>>(
            qkTh, qkTl, 2 * C_Q, qkTh + C_Q, qkTl + C_Q, 2 * C_Q, C_Q,
            nullptr, nullptr, nullptr, nullptr, nullptr, nullptr, nullptr,
            scores, D);

        // res[c,i] = sum_j (Vh+Vl)[c,j] * f16(exp(S[i,j])/D[i]); z=0->out, z>0->part
        feat5<<<dim3(HW_N / 128, C_IN / 128, 4), dim3(256), 0, stream>>>(
            Vh, Vl, scores, D, outb, part, HW_N / 4);

        // out = alpha * (out + part0 + part1 + part2)
        reduce_alpha3<<<dim3((C_IN * HW_N / 4) / 256), dim3(256), 0, stream>>>(
            outb, (const float4*)part, (size_t)C_IN * HW_N / 4, alpha);
    }
}